// Round 6
// baseline (810.976 us; speedup 1.0000x reference)
//
#include <hip/hip_runtime.h>
#include <cstdint>
#include <cstddef>

// GAT forward: query = ufea@W^T + b; S = leaky2((q@inter^T)/sqrt(D)) masked by adj;
// out = softmax(S) @ inter.   N=10000 users, M=12000 items, D=128.
// R6: adj (480MB int32) pre-compressed 32:1 into a row-major bitmask (15MB) by a
// perfectly-sequential stream kernel. Fused reads 8 broadcast mask dwords per
// tile per wave (L2-resident) instead of 4KB of scattered HBM — removes the
// 32k-interleaved-stream DRAM thrash that pinned R3-R5 at ~215us.
// Fused structure = R5: 64-item tiles, 1 barrier/tile, K+V LDS dbuf.

#define N_USERS 10000
#define N_ITEMS 12000
#define HD      128
#define QROWS   10048      // 157*64 padded user rows
#define NCHUNK  16
#define TILE    64
#define NTILES  188        // ceil(12000/64); tile 187 has 32 valid items
#define UBLOCKS 157
#define KT_PITCH 12032     // interT row pitch (pad so tail-tile reads stay in-buffer)
#define MROW    375        // bitmask dwords per user row (12000/32)
#define NMASK   3750000    // total bitmask dwords

typedef __bf16 bf16x8 __attribute__((ext_vector_type(8)));
typedef __bf16 bf16x4 __attribute__((ext_vector_type(4)));
typedef __bf16 bf16x2 __attribute__((ext_vector_type(2)));
typedef float  f32x4  __attribute__((ext_vector_type(4)));
typedef int    i32x4  __attribute__((ext_vector_type(4)));

typedef const __attribute__((address_space(1))) unsigned int g_u32;
typedef __attribute__((address_space(3))) unsigned int l_u32;

// ---------------- adj int32 -> bitmask (32:1), perfectly sequential stream ----------------
__global__ __launch_bounds__(256) void compress_adj_kernel(const int* __restrict__ adj,
                                                           unsigned int* __restrict__ mask) {
    const int d = blockIdx.x * 256 + threadIdx.x;   // output dword index
    if (d >= NMASK) return;
    const int* p = adj + (size_t)d * 32;            // 12000%32==0: dword never straddles a row
    unsigned int m = 0;
    #pragma unroll
    for (int j = 0; j < 8; ++j) {
        i32x4 v = *(const i32x4*)(p + j * 4);
        m |= (unsigned int)(v[0] > 0) << (j * 4 + 0);
        m |= (unsigned int)(v[1] > 0) << (j * 4 + 1);
        m |= (unsigned int)(v[2] > 0) << (j * 4 + 2);
        m |= (unsigned int)(v[3] > 0) << (j * 4 + 3);
    }
    mask[d] = m;
}

// ---------------- inter -> bf16 (row-major) + bf16 transposed copy ----------------
__global__ __launch_bounds__(256) void cast_inter_kernel(const float* __restrict__ inter,
                                                         __bf16* __restrict__ kg,
                                                         __bf16* __restrict__ ktg) {
    __shared__ __bf16 Tl[128 * 72];   // [d][item_local], pitch 72 (16B-aligned rows)
    const int t  = threadIdx.x;
    const int i0 = blockIdx.x * 64;
    for (int it = 0; it < 8; ++it) {
        int g   = it * 256 + t;
        int row = g >> 5;            // 0..63 item_local
        int d   = (g & 31) * 4;      // 0..124
        int item = i0 + row;
        if (item < N_ITEMS) {
            f32x4 v = *(const f32x4*)(inter + (size_t)item * HD + d);
            __bf16 b0 = (__bf16)v.x, b1 = (__bf16)v.y, b2 = (__bf16)v.z, b3 = (__bf16)v.w;
            bf16x4 pk = {b0, b1, b2, b3};
            *(bf16x4*)(kg + (size_t)item * HD + d) = pk;
            Tl[(d + 0) * 72 + row] = b0;
            Tl[(d + 1) * 72 + row] = b1;
            Tl[(d + 2) * 72 + row] = b2;
            Tl[(d + 3) * 72 + row] = b3;
        } else {
            Tl[(d + 0) * 72 + row] = (__bf16)0.f;
            Tl[(d + 1) * 72 + row] = (__bf16)0.f;
            Tl[(d + 2) * 72 + row] = (__bf16)0.f;
            Tl[(d + 3) * 72 + row] = (__bf16)0.f;
        }
    }
    __syncthreads();
    const int d  = t >> 1;
    const int jb = (t & 1) * 32;
    if (i0 + jb < N_ITEMS) {          // 12000 % 32 == 0 so validity is per-half
        #pragma unroll
        for (int k = 0; k < 4; ++k) {
            bf16x8 v = *(const bf16x8*)&Tl[d * 72 + jb + k * 8];
            *(bf16x8*)(ktg + (size_t)d * KT_PITCH + i0 + jb + k * 8) = v;
        }
    }
}

// ---------------- query = ufea @ W^T + b  (bf16 MFMA, output bf16) ----------------
__global__ __launch_bounds__(256) void query_kernel(const float* __restrict__ ufea,
                                                    const float* __restrict__ W,
                                                    const float* __restrict__ bias,
                                                    __bf16* __restrict__ qg) {
    const int lane = threadIdx.x & 63, wave = threadIdx.x >> 6;
    const int n = lane & 15, qd = lane >> 4;
    const int user0 = blockIdx.x * 64 + wave * 16;
    int arow = user0 + n; if (arow > N_USERS - 1) arow = N_USERS - 1;

    bf16x8 af[4];
    #pragma unroll
    for (int kk = 0; kk < 4; ++kk) {
        const float* p = ufea + (size_t)arow * HD + kk * 32 + qd * 8;
        f32x4 lo = *(const f32x4*)p, hi = *(const f32x4*)(p + 4);
        bf16x8 a;
        a[0]=(__bf16)lo.x; a[1]=(__bf16)lo.y; a[2]=(__bf16)lo.z; a[3]=(__bf16)lo.w;
        a[4]=(__bf16)hi.x; a[5]=(__bf16)hi.y; a[6]=(__bf16)hi.z; a[7]=(__bf16)hi.w;
        af[kk] = a;
    }
    #pragma unroll
    for (int nt = 0; nt < 8; ++nt) {
        f32x4 acc = {0.f, 0.f, 0.f, 0.f};
        #pragma unroll
        for (int kk = 0; kk < 4; ++kk) {
            const float* p = W + (size_t)(nt * 16 + n) * HD + kk * 32 + qd * 8;
            f32x4 lo = *(const f32x4*)p, hi = *(const f32x4*)(p + 4);
            bf16x8 b;
            b[0]=(__bf16)lo.x; b[1]=(__bf16)lo.y; b[2]=(__bf16)lo.z; b[3]=(__bf16)lo.w;
            b[4]=(__bf16)hi.x; b[5]=(__bf16)hi.y; b[6]=(__bf16)hi.z; b[7]=(__bf16)hi.w;
            acc = __builtin_amdgcn_mfma_f32_16x16x32_bf16(af[kk], b, acc, 0, 0, 0);
        }
        const float bv = bias[nt * 16 + n];
        #pragma unroll
        for (int r = 0; r < 4; ++r) {
            int row = user0 + qd * 4 + r;
            qg[(size_t)row * HD + nt * 16 + n] = (__bf16)(acc[r] + bv);
        }
    }
}

// ---------------- fused: S = q@k^T, mask+leaky+exp, O += P@V, l += rowsum ----------------
// 64-item tiles; 1 barrier/tile; K+V dbuf via global_load_lds; bitmask adj (broadcast dwords).
// Item permutation within tile: MFMA subtile nt covers item j0 + (nt>>1)*32 + 2n + (nt&1).
__global__ __launch_bounds__(256, 2) void fused_kernel(const __bf16* __restrict__ qg,
                                                       const __bf16* __restrict__ kg,
                                                       const __bf16* __restrict__ ktg,
                                                       const unsigned int* __restrict__ mask,
                                                       float* __restrict__ Opart,
                                                       float* __restrict__ lpart) {
    __shared__ __bf16 Kbuf[2][16 * 512];  // chunk c=(nt*4+kk): K[item(nt,n)][kk*32+qd*8..]
    __shared__ __bf16 Vbuf[2][16 * 512];  // chunk c=(dt*2+kc): V_T[dt*16+n][j0+kc*32+qd*8..]
    __shared__ __bf16 Pl[4][16 * 72];     // per-wave P: [user][item], pitch 72
    const int lane = threadIdx.x & 63, wave = threadIdx.x >> 6;
    const int n = lane & 15, qd = lane >> 4;
    const int user0 = blockIdx.y * 64 + wave * 16;
    const int chunk = blockIdx.x;          // chunk-major grid: chunk ~ XCD (L2 affinity)
    const int t0 = (chunk * NTILES) / NCHUNK;
    const int t1 = ((chunk + 1) * NTILES) / NCHUNK;
    const float SC = (float)(1.4426950408889634 * 0.08838834764831845); // log2(e)/sqrt(128)

    bf16x8 qf[4];
    #pragma unroll
    for (int kk = 0; kk < 4; ++kk)
        qf[kk] = *(const bf16x8*)(qg + (size_t)(user0 + n) * HD + kk * 32 + qd * 8);

    f32x4 Oacc[8];
    #pragma unroll
    for (int dt = 0; dt < 8; ++dt) Oacc[dt] = (f32x4){0.f, 0.f, 0.f, 0.f};
    float lacc[4] = {0.f, 0.f, 0.f, 0.f};

    size_t mOff[4];   // bitmask row offsets (dwords) for rows user0+qd*4+r
    #pragma unroll
    for (int r = 0; r < 4; ++r) {
        int u = user0 + qd * 4 + r;
        if (u > N_USERS - 1) u = N_USERS - 1;
        mOff[r] = (size_t)u * MROW;
    }
    __bf16* pw = &Pl[wave][0];

    // stage tile t's K+V into buffer b: 8 async 1KB chunks per wave (4 K + 4 V)
    auto stage = [&](int t, int b) {
        const int j0s = t * TILE;
        #pragma unroll
        for (int j = 0; j < 4; ++j) {
            const int c = wave * 4 + j;          // K chunk: nt = wave, kk = j
            int row = j0s + (wave >> 1) * 32 + 2 * n + (wave & 1);
            if (row > N_ITEMS - 1) row = N_ITEMS - 1;
            const __bf16* src = kg + (size_t)row * HD + j * 32 + qd * 8;
            __builtin_amdgcn_global_load_lds((g_u32*)src, (l_u32*)(&Kbuf[b][c * 512]), 16, 0, 0);
        }
        #pragma unroll
        for (int j = 0; j < 4; ++j) {
            const int c = wave * 4 + j;          // V chunk: dt = c>>1, kc = c&1
            const int dt = c >> 1, kc = c & 1;
            const __bf16* src = ktg + (size_t)(dt * 16 + n) * KT_PITCH + j0s + kc * 32 + qd * 8;
            __builtin_amdgcn_global_load_lds((g_u32*)src, (l_u32*)(&Vbuf[b][c * 512]), 16, 0, 0);
        }
    };
    // bitmask loads for tile t: md[h][r] = mask dword for items [j0+h*32, +32), row r.
    // Address uniform across the 16 lanes of a quad -> hardware broadcast, L2-hit.
    auto load_mask = [&](int t, unsigned int md[2][4]) {
        #pragma unroll
        for (int h = 0; h < 2; ++h)
            #pragma unroll
            for (int r = 0; r < 4; ++r)
                md[h][r] = mask[mOff[r] + t * 2 + h];   // t*2+h<=375: pad slack in buffer
    };

    // prologue
    stage(t0, 0);
    unsigned int md[2][4];
    load_mask(t0, md);

    for (int t = t0; t < t1; ++t) {
        const int cur = (t - t0) & 1;
        const int j0 = t * TILE;
        __syncthreads();   // drains stage(t); one full tile of compute follows

        unsigned int mdn[2][4];
        if (t + 1 < t1) {
            load_mask(t + 1, mdn);
            stage(t + 1, cur ^ 1);
        }

        // S = q @ K^T (16 MFMAs), B-frags lane-linear from Kbuf (conflict-free b128)
        f32x4 S[4];
        #pragma unroll
        for (int nt = 0; nt < 4; ++nt) S[nt] = (f32x4){0.f, 0.f, 0.f, 0.f};
        #pragma unroll
        for (int nt = 0; nt < 4; ++nt) {
            #pragma unroll
            for (int kk = 0; kk < 4; ++kk) {
                bf16x8 b = *(const bf16x8*)(&Kbuf[cur][(nt * 4 + kk) * 512 + lane * 8]);
                S[nt] = __builtin_amdgcn_mfma_f32_16x16x32_bf16(qf[kk], b, S[nt], 0, 0, 0);
            }
        }
        // mask (bit extract) + leaky2 + exp2 -> P pairs (bf16x2) at true item positions
        #pragma unroll
        for (int r = 0; r < 4; ++r) {
            #pragma unroll
            for (int h = 0; h < 2; ++h) {
                const int colb = j0 + h * 32 + 2 * n;   // item of parity 0
                float p01[2];
                #pragma unroll
                for (int par = 0; par < 2; ++par) {
                    const int nt = h * 2 + par;
                    float s = S[nt][r] * SC;
                    s = fminf(s, s + s);                // leaky_relu(slope 2), pre-scaled
                    const bool on = (colb + par < N_ITEMS) && ((md[h][r] >> (2 * n + par)) & 1u);
                    float p = on ? __builtin_amdgcn_exp2f(s) : 0.f;
                    lacc[r] += p;
                    p01[par] = p;
                }
                bf16x2 pk = {(__bf16)p01[0], (__bf16)p01[1]};
                *(bf16x2*)(pw + (qd * 4 + r) * 72 + h * 32 + 2 * n) = pk;
            }
        }
        // P (C-layout) -> A-layout via per-wave LDS; PV (16 MFMAs)
        #pragma unroll
        for (int kc = 0; kc < 2; ++kc) {
            bf16x8 af = *(const bf16x8*)(pw + n * 72 + kc * 32 + qd * 8);
            #pragma unroll
            for (int dt = 0; dt < 8; ++dt) {
                bf16x8 b = *(const bf16x8*)(&Vbuf[cur][(dt * 2 + kc) * 512 + lane * 8]);
                Oacc[dt] = __builtin_amdgcn_mfma_f32_16x16x32_bf16(af, b, Oacc[dt], 0, 0, 0);
            }
        }
        // rotate mask registers
        #pragma unroll
        for (int h = 0; h < 2; ++h)
            #pragma unroll
            for (int r = 0; r < 4; ++r)
                md[h][r] = mdn[h][r];
    }

    // reduce l across the 16 lanes of each quad (lanes jointly cover all items)
    #pragma unroll
    for (int r = 0; r < 4; ++r) {
        float v = lacc[r];
        v += __shfl_xor(v, 1);
        v += __shfl_xor(v, 2);
        v += __shfl_xor(v, 4);
        v += __shfl_xor(v, 8);
        lacc[r] = v;
    }
    const size_t cb = (size_t)chunk * QROWS;
    #pragma unroll
    for (int r = 0; r < 4; ++r) {
        const int user = user0 + qd * 4 + r;
        if (user < N_USERS) {
            #pragma unroll
            for (int dt = 0; dt < 8; ++dt)
                Opart[(cb + user) * HD + dt * 16 + n] = Oacc[dt][r];
            if (n == 0) lpart[cb + user] = lacc[r];
        }
    }
}

// ---------------- combine partials: out = (sum_c O_c) / (sum_c l_c) ----------------
__global__ __launch_bounds__(256) void combine_kernel(const float* __restrict__ Opart,
                                                      const float* __restrict__ lpart,
                                                      float* __restrict__ out) {
    const int g = blockIdx.x * 256 + threadIdx.x;   // 320000 threads exactly
    const int base = g * 4;
    const int user = base >> 7;
    const int d = base & 127;
    f32x4 acc = {0.f, 0.f, 0.f, 0.f};
    float l = 0.f;
    #pragma unroll
    for (int c = 0; c < NCHUNK; ++c) {
        acc += *(const f32x4*)(Opart + ((size_t)c * QROWS + user) * HD + d);
        l += lpart[(size_t)c * QROWS + user];
    }
    f32x4 res = acc / l;
    *(f32x4*)(out + (size_t)user * HD + d) = res;
}

extern "C" void kernel_launch(void* const* d_in, const int* in_sizes, int n_in,
                              void* d_out, int out_size, void* d_ws, size_t ws_size,
                              hipStream_t stream) {
    const float* ufea = (const float*)d_in[0];
    const float* inter = (const float*)d_in[1];
    const int*   adj  = (const int*)d_in[2];
    const float* W    = (const float*)d_in[3];
    const float* bias = (const float*)d_in[4];
    float* out = (float*)d_out;

    char* ws = (char*)d_ws;
    // layout (bytes):
    //   qg    : 10048*128*2       = 2,572,288
    //   kg    : 12000*128*2       = 3,072,000
    //   ktg   : 128*12032*2       = 3,080,192
    //   maskb : 3,750,000*4 +pad  = 15,001,600
    //   Opart : 16*10048*128*4    = 82,313,216
    //   lpart : 16*10048*4        = 643,072          total ~106.7 MB
    __bf16*       qg   = (__bf16*)(ws);
    __bf16*       kg   = (__bf16*)(ws + 2572288);
    __bf16*       ktg  = (__bf16*)(ws + 5644288);
    unsigned int* mb   = (unsigned int*)(ws + 8724480);
    float*        Opart = (float*)(ws + 23726080);
    float*        lpart = (float*)(ws + 106039296);

    compress_adj_kernel<<<dim3(14649), dim3(256), 0, stream>>>(adj, mb);
    cast_inter_kernel<<<dim3(188), dim3(256), 0, stream>>>(inter, kg, ktg);
    query_kernel<<<dim3(UBLOCKS), dim3(256), 0, stream>>>(ufea, W, bias, qg);
    fused_kernel<<<dim3(NCHUNK, UBLOCKS), dim3(256), 0, stream>>>(qg, kg, ktg, mb, Opart, lpart);
    combine_kernel<<<dim3(1250), dim3(256), 0, stream>>>(Opart, lpart, out);
}

// Round 7
// 687.801 us; speedup vs baseline: 1.1791x; 1.1791x over previous
//
#include <hip/hip_runtime.h>
#include <cstdint>
#include <cstddef>

// GAT forward: query = ufea@W^T + b; S = leaky2((q@inter^T)/sqrt(D)) masked by adj;
// out = softmax(S) @ inter.   N=10000 users, M=12000 items, D=128.
// R7: DS-bound fix — each wave computes TWO 16-user M-tiles (32 users), reusing
// every K/V B-fragment LDS read for two MFMAs (B-traffic per user halves; block
// = 128 users; block-tiles halve). adj read inline (i32x4 per row via col=4n+nt
// item permutation), drained for free by the pre-compute barrier. 50 KB LDS.

#define N_USERS 10000
#define N_ITEMS 12000
#define HD      128
#define QROWS   10112      // 79*128 padded user rows
#define NCHUNK  16
#define TILE    64
#define NTILES  188        // ceil(12000/64); tile 187 has 32 valid items
#define UBLOCKS 79         // fused user-blocks of 128
#define QBLOCKS 158        // query blocks of 64
#define KT_PITCH 12032     // interT row pitch (zero-padded cols 12000..12031)

typedef __bf16 bf16x8 __attribute__((ext_vector_type(8)));
typedef __bf16 bf16x4 __attribute__((ext_vector_type(4)));
typedef __bf16 bf16x2 __attribute__((ext_vector_type(2)));
typedef float  f32x4  __attribute__((ext_vector_type(4)));
typedef int    i32x4  __attribute__((ext_vector_type(4)));

typedef const __attribute__((address_space(1))) unsigned int g_u32;
typedef __attribute__((address_space(3))) unsigned int l_u32;

// ---------------- inter -> bf16 (row-major) + bf16 transposed copy ----------------
__global__ __launch_bounds__(256) void cast_inter_kernel(const float* __restrict__ inter,
                                                         __bf16* __restrict__ kg,
                                                         __bf16* __restrict__ ktg) {
    __shared__ __bf16 Tl[128 * 72];   // [d][item_local], pitch 72 (16B-aligned rows)
    const int t  = threadIdx.x;
    const int i0 = blockIdx.x * 64;
    for (int it = 0; it < 8; ++it) {
        int g   = it * 256 + t;
        int row = g >> 5;            // 0..63 item_local
        int d   = (g & 31) * 4;      // 0..124
        int item = i0 + row;
        if (item < N_ITEMS) {
            f32x4 v = *(const f32x4*)(inter + (size_t)item * HD + d);
            __bf16 b0 = (__bf16)v.x, b1 = (__bf16)v.y, b2 = (__bf16)v.z, b3 = (__bf16)v.w;
            bf16x4 pk = {b0, b1, b2, b3};
            *(bf16x4*)(kg + (size_t)item * HD + d) = pk;
            Tl[(d + 0) * 72 + row] = b0;
            Tl[(d + 1) * 72 + row] = b1;
            Tl[(d + 2) * 72 + row] = b2;
            Tl[(d + 3) * 72 + row] = b3;
        } else {
            Tl[(d + 0) * 72 + row] = (__bf16)0.f;
            Tl[(d + 1) * 72 + row] = (__bf16)0.f;
            Tl[(d + 2) * 72 + row] = (__bf16)0.f;
            Tl[(d + 3) * 72 + row] = (__bf16)0.f;
        }
    }
    __syncthreads();
    const int d  = t >> 1;
    const int jb = (t & 1) * 32;
    // no validity guard: invalid items were zero-filled in Tl -> ktg pad = 0.0
    #pragma unroll
    for (int k = 0; k < 4; ++k) {
        bf16x8 v = *(const bf16x8*)&Tl[d * 72 + jb + k * 8];
        *(bf16x8*)(ktg + (size_t)d * KT_PITCH + i0 + jb + k * 8) = v;
    }
}

// ---------------- query = ufea @ W^T + b  (bf16 MFMA, output bf16) ----------------
__global__ __launch_bounds__(256) void query_kernel(const float* __restrict__ ufea,
                                                    const float* __restrict__ W,
                                                    const float* __restrict__ bias,
                                                    __bf16* __restrict__ qg) {
    const int lane = threadIdx.x & 63, wave = threadIdx.x >> 6;
    const int n = lane & 15, qd = lane >> 4;
    const int user0 = blockIdx.x * 64 + wave * 16;
    int arow = user0 + n; if (arow > N_USERS - 1) arow = N_USERS - 1;

    bf16x8 af[4];
    #pragma unroll
    for (int kk = 0; kk < 4; ++kk) {
        const float* p = ufea + (size_t)arow * HD + kk * 32 + qd * 8;
        f32x4 lo = *(const f32x4*)p, hi = *(const f32x4*)(p + 4);
        bf16x8 a;
        a[0]=(__bf16)lo.x; a[1]=(__bf16)lo.y; a[2]=(__bf16)lo.z; a[3]=(__bf16)lo.w;
        a[4]=(__bf16)hi.x; a[5]=(__bf16)hi.y; a[6]=(__bf16)hi.z; a[7]=(__bf16)hi.w;
        af[kk] = a;
    }
    #pragma unroll
    for (int nt = 0; nt < 8; ++nt) {
        f32x4 acc = {0.f, 0.f, 0.f, 0.f};
        #pragma unroll
        for (int kk = 0; kk < 4; ++kk) {
            const float* p = W + (size_t)(nt * 16 + n) * HD + kk * 32 + qd * 8;
            f32x4 lo = *(const f32x4*)p, hi = *(const f32x4*)(p + 4);
            bf16x8 b;
            b[0]=(__bf16)lo.x; b[1]=(__bf16)lo.y; b[2]=(__bf16)lo.z; b[3]=(__bf16)lo.w;
            b[4]=(__bf16)hi.x; b[5]=(__bf16)hi.y; b[6]=(__bf16)hi.z; b[7]=(__bf16)hi.w;
            acc = __builtin_amdgcn_mfma_f32_16x16x32_bf16(af[kk], b, acc, 0, 0, 0);
        }
        const float bv = bias[nt * 16 + n];
        #pragma unroll
        for (int r = 0; r < 4; ++r) {
            int row = user0 + qd * 4 + r;   // < QROWS; pad rows hold clamped dup (unused)
            qg[(size_t)row * HD + nt * 16 + n] = (__bf16)(acc[r] + bv);
        }
    }
}

// ---------------- fused: S = q@k^T, mask+leaky+exp, O += P@V, l += rowsum ----------------
// Wave = 32 users (two 16-user groups sharing every B-frag). 64-item tiles,
// item permutation: MFMA subtile nt covers item j0 + 4n + nt.
// 2-barrier loop; adj i32x4 loads issued between the barriers (drained for free).
__global__ __launch_bounds__(256, 2) void fused_kernel(const __bf16* __restrict__ qg,
                                                       const __bf16* __restrict__ kg,
                                                       const __bf16* __restrict__ ktg,
                                                       const int* __restrict__ adj,
                                                       float* __restrict__ Opart,
                                                       float* __restrict__ lpart) {
    __shared__ __bf16 Kbuf[16 * 512];     // chunk c=(nt*4+kk): K[j0+4n+nt][kk*32+qd*8..]
    __shared__ __bf16 Vbuf[16 * 512];     // chunk c=(dt*2+kc): V_T[dt*16+n][j0+kc*32+qd*8..]
    __shared__ __bf16 Pl[4][32 * 72];     // per-wave P: [user 0..31][item 0..63], pitch 72
    const int lane = threadIdx.x & 63, wave = threadIdx.x >> 6;
    const int n = lane & 15, qd = lane >> 4;
    const int user0 = blockIdx.y * 128 + wave * 32;   // wave covers users user0..user0+31
    const int chunk = blockIdx.x;          // chunk-major grid: chunk ~ XCD (L2 affinity)
    const int t0 = (chunk * NTILES) / NCHUNK;
    const int t1 = ((chunk + 1) * NTILES) / NCHUNK;
    const float SC = (float)(1.4426950408889634 * 0.08838834764831845); // log2(e)/sqrt(128)

    bf16x8 qf[2][4];
    #pragma unroll
    for (int g = 0; g < 2; ++g)
        #pragma unroll
        for (int kk = 0; kk < 4; ++kk)
            qf[g][kk] = *(const bf16x8*)(qg + (size_t)(user0 + g * 16 + n) * HD + kk * 32 + qd * 8);

    f32x4 Oacc[2][8];
    #pragma unroll
    for (int g = 0; g < 2; ++g)
        #pragma unroll
        for (int dt = 0; dt < 8; ++dt) Oacc[g][dt] = (f32x4){0.f, 0.f, 0.f, 0.f};
    float lacc[2][4] = {{0.f,0.f,0.f,0.f},{0.f,0.f,0.f,0.f}};

    int adjOff[2][4];   // element offsets (10000*12000 < 2^31)
    #pragma unroll
    for (int g = 0; g < 2; ++g)
        #pragma unroll
        for (int r = 0; r < 4; ++r) {
            int u = user0 + g * 16 + qd * 4 + r;
            if (u > N_USERS - 1) u = N_USERS - 1;
            adjOff[g][r] = u * N_ITEMS;
        }
    __bf16* pw = &Pl[wave][0];

    for (int t = t0; t < t1; ++t) {
        const int j0 = t * TILE;
        __syncthreads();   // barrier1: all waves done reading LDS for tile t-1

        // async stage K+V for tile t (8 x 1KB chunks per wave)
        #pragma unroll
        for (int j = 0; j < 4; ++j) {
            const int c = wave * 4 + j;            // K chunk: nt = wave, kk = j
            int row = j0 + 4 * n + wave;
            if (row > N_ITEMS - 1) row = N_ITEMS - 1;
            const __bf16* src = kg + (size_t)row * HD + j * 32 + qd * 8;
            __builtin_amdgcn_global_load_lds((g_u32*)src, (l_u32*)(&Kbuf[c * 512]), 16, 0, 0);
        }
        #pragma unroll
        for (int j = 0; j < 4; ++j) {
            const int c = wave * 4 + j;            // V chunk: dt = c>>1, kc = c&1
            const int dt = c >> 1, kc = c & 1;
            const __bf16* src = ktg + (size_t)(dt * 16 + n) * KT_PITCH + j0 + kc * 32 + qd * 8;
            __builtin_amdgcn_global_load_lds((g_u32*)src, (l_u32*)(&Vbuf[c * 512]), 16, 0, 0);
        }
        // adj loads for tile t: one i32x4 per (group,row) covering cols 4n..4n+3
        i32x4 av[2][4];
        {
            int col4 = j0 + 4 * n;
            if (col4 > N_ITEMS - 4) col4 = N_ITEMS - 4;
            #pragma unroll
            for (int g = 0; g < 2; ++g)
                #pragma unroll
                for (int r = 0; r < 4; ++r)
                    av[g][r] = __builtin_nontemporal_load((const i32x4*)(adj + adjOff[g][r] + col4));
        }
        __syncthreads();   // barrier2: vmcnt(0) drains staging AND adj loads

        // QK: 16 B-frag reads, each feeding MFMAs for both user groups (32 MFMAs)
        f32x4 S[2][4];
        #pragma unroll
        for (int g = 0; g < 2; ++g)
            #pragma unroll
            for (int nt = 0; nt < 4; ++nt) S[g][nt] = (f32x4){0.f, 0.f, 0.f, 0.f};
        #pragma unroll
        for (int nt = 0; nt < 4; ++nt) {
            #pragma unroll
            for (int kk = 0; kk < 4; ++kk) {
                bf16x8 b = *(const bf16x8*)(&Kbuf[(nt * 4 + kk) * 512 + lane * 8]);
                S[0][nt] = __builtin_amdgcn_mfma_f32_16x16x32_bf16(qf[0][kk], b, S[0][nt], 0, 0, 0);
                S[1][nt] = __builtin_amdgcn_mfma_f32_16x16x32_bf16(qf[1][kk], b, S[1][nt], 0, 0, 0);
            }
        }
        // mask + leaky2 + exp2 -> P quads (bf16x4 = items 4n..4n+3 of row)
        #pragma unroll
        for (int g = 0; g < 2; ++g) {
            #pragma unroll
            for (int r = 0; r < 4; ++r) {
                bf16x4 pk;
                #pragma unroll
                for (int nt = 0; nt < 4; ++nt) {
                    float s = S[g][nt][r] * SC;
                    s = fminf(s, s + s);            // leaky_relu(slope 2), pre-scaled
                    const bool on = (j0 + 4 * n + nt < N_ITEMS) && (av[g][r][nt] > 0);
                    float p = on ? __builtin_amdgcn_exp2f(s) : 0.f;
                    lacc[g][r] += p;
                    pk[nt] = (__bf16)p;
                }
                *(bf16x4*)(pw + (g * 16 + qd * 4 + r) * 72 + 4 * n) = pk;
            }
        }
        // PV: 16 B-frag reads, each feeding both groups (32 MFMAs)
        #pragma unroll
        for (int kc = 0; kc < 2; ++kc) {
            bf16x8 af0 = *(const bf16x8*)(pw + (0 * 16 + n) * 72 + kc * 32 + qd * 8);
            bf16x8 af1 = *(const bf16x8*)(pw + (1 * 16 + n) * 72 + kc * 32 + qd * 8);
            #pragma unroll
            for (int dt = 0; dt < 8; ++dt) {
                bf16x8 b = *(const bf16x8*)(&Vbuf[(dt * 2 + kc) * 512 + lane * 8]);
                Oacc[0][dt] = __builtin_amdgcn_mfma_f32_16x16x32_bf16(af0, b, Oacc[0][dt], 0, 0, 0);
                Oacc[1][dt] = __builtin_amdgcn_mfma_f32_16x16x32_bf16(af1, b, Oacc[1][dt], 0, 0, 0);
            }
        }
    }

    // reduce l across the 16 lanes of each quad (lanes jointly cover all items)
    #pragma unroll
    for (int g = 0; g < 2; ++g)
        #pragma unroll
        for (int r = 0; r < 4; ++r) {
            float v = lacc[g][r];
            v += __shfl_xor(v, 1);
            v += __shfl_xor(v, 2);
            v += __shfl_xor(v, 4);
            v += __shfl_xor(v, 8);
            lacc[g][r] = v;
        }
    const size_t cb = (size_t)chunk * QROWS;
    #pragma unroll
    for (int g = 0; g < 2; ++g)
        #pragma unroll
        for (int r = 0; r < 4; ++r) {
            const int user = user0 + g * 16 + qd * 4 + r;
            if (user < N_USERS) {
                #pragma unroll
                for (int dt = 0; dt < 8; ++dt)
                    Opart[(cb + user) * HD + dt * 16 + n] = Oacc[g][dt][r];
                if (n == 0) lpart[cb + user] = lacc[g][r];
            }
        }
}

// ---------------- combine partials: out = (sum_c O_c) / (sum_c l_c) ----------------
__global__ __launch_bounds__(256) void combine_kernel(const float* __restrict__ Opart,
                                                      const float* __restrict__ lpart,
                                                      float* __restrict__ out) {
    const int g = blockIdx.x * 256 + threadIdx.x;   // 323584 threads exactly
    const int base = g * 4;
    const int user = base >> 7;
    const int d = base & 127;
    f32x4 acc = {0.f, 0.f, 0.f, 0.f};
    float l = 0.f;
    #pragma unroll
    for (int c = 0; c < NCHUNK; ++c) {
        acc += *(const f32x4*)(Opart + ((size_t)c * QROWS + user) * HD + d);
        l += lpart[(size_t)c * QROWS + user];
    }
    if (user < N_USERS) {
        f32x4 res = acc / l;
        *(f32x4*)(out + (size_t)user * HD + d) = res;
    }
}

extern "C" void kernel_launch(void* const* d_in, const int* in_sizes, int n_in,
                              void* d_out, int out_size, void* d_ws, size_t ws_size,
                              hipStream_t stream) {
    const float* ufea = (const float*)d_in[0];
    const float* inter = (const float*)d_in[1];
    const int*   adj  = (const int*)d_in[2];
    const float* W    = (const float*)d_in[3];
    const float* bias = (const float*)d_in[4];
    float* out = (float*)d_out;

    char* ws = (char*)d_ws;
    // layout (bytes):
    //   qg    : 10112*128*2       = 2,588,672
    //   kg    : 12000*128*2       = 3,072,000
    //   ktg   : 128*12032*2       = 3,080,192
    //   Opart : 16*10112*128*4    = 82,837,504
    //   lpart : 16*10112*4        = 647,168          total ~92.2 MB
    __bf16* qg   = (__bf16*)(ws);
    __bf16* kg   = (__bf16*)(ws + 2588672);
    __bf16* ktg  = (__bf16*)(ws + 5660672);
    float*  Opart = (float*)(ws + 8740864);
    float*  lpart = (float*)(ws + 91578368);

    cast_inter_kernel<<<dim3(188), dim3(256), 0, stream>>>(inter, kg, ktg);
    query_kernel<<<dim3(QBLOCKS), dim3(256), 0, stream>>>(ufea, W, bias, qg);
    fused_kernel<<<dim3(NCHUNK, UBLOCKS), dim3(256), 0, stream>>>(qg, kg, ktg, adj, Opart, lpart);
    combine_kernel<<<dim3(1264), dim3(256), 0, stream>>>(Opart, lpart, out);
}